// Round 3
// baseline (233.080 us; speedup 1.0000x reference)
//
#include <hip/hip_runtime.h>

#define NKEYS 64

typedef float vfloat4 __attribute__((ext_vector_type(4)));

// out[i] = t[x[i]] where t is a 64-entry table derived from (keys, b):
//   t[v] = b[k] if keys[k] == (float)v for integral v in [0,64), else 0.
// Lookup via ds_bpermute: lane l of each wave holds t[l] (wave64 == NKEYS),
// so t[v] = bpermute(v*4, tval) — conflict-free crossbar, no LDS banking.
__global__ __launch_bounds__(256) void sel_xform_kernel(
    const int4* __restrict__ in,
    const float* __restrict__ b,
    const float* __restrict__ keys,
    float* __restrict__ out,
    int nvec, int ntail, const int* __restrict__ in_tail, float* __restrict__ out_tail)
{
    __shared__ float t[NKEYS];
    const int tid = threadIdx.x;
    if (tid < NKEYS) t[tid] = 0.0f;
    __syncthreads();
    if (tid < NKEYS) {
        const float kv = keys[tid];
        const int iv = (int)kv;
        if ((float)iv == kv && iv >= 0 && iv < NKEYS) {
            t[iv] = b[tid];   // keys unique -> no write race
        }
    }
    __syncthreads();

    // Per-lane table register: lane l holds t[l]. Stride-1 LDS read, 2-way
    // bank alias across wave64 -> free (m136).
    const int tv_i = __float_as_int(t[tid & 63]);

    int i = blockIdx.x * blockDim.x + tid;
    const int stride = gridDim.x * blockDim.x;

    if (i < nvec) {
        int4 v = in[i];
        int inext = i + stride;
        while (inext < nvec) {
            const int4 vn = in[inext];   // keep next load in flight
            vfloat4 o;
            o.x = __int_as_float(__builtin_amdgcn_ds_bpermute(v.x << 2, tv_i));
            o.y = __int_as_float(__builtin_amdgcn_ds_bpermute(v.y << 2, tv_i));
            o.z = __int_as_float(__builtin_amdgcn_ds_bpermute(v.z << 2, tv_i));
            o.w = __int_as_float(__builtin_amdgcn_ds_bpermute(v.w << 2, tv_i));
            if ((unsigned)v.x >= NKEYS) o.x = 0.0f;
            if ((unsigned)v.y >= NKEYS) o.y = 0.0f;
            if ((unsigned)v.z >= NKEYS) o.z = 0.0f;
            if ((unsigned)v.w >= NKEYS) o.w = 0.0f;
            __builtin_nontemporal_store(o, (vfloat4*)&out[i << 2]);
            v = vn;
            i = inext;
            inext += stride;
        }
        // drain the pipeline: last element this thread owns
        vfloat4 o;
        o.x = __int_as_float(__builtin_amdgcn_ds_bpermute(v.x << 2, tv_i));
        o.y = __int_as_float(__builtin_amdgcn_ds_bpermute(v.y << 2, tv_i));
        o.z = __int_as_float(__builtin_amdgcn_ds_bpermute(v.z << 2, tv_i));
        o.w = __int_as_float(__builtin_amdgcn_ds_bpermute(v.w << 2, tv_i));
        if ((unsigned)v.x >= NKEYS) o.x = 0.0f;
        if ((unsigned)v.y >= NKEYS) o.y = 0.0f;
        if ((unsigned)v.z >= NKEYS) o.z = 0.0f;
        if ((unsigned)v.w >= NKEYS) o.w = 0.0f;
        __builtin_nontemporal_store(o, (vfloat4*)&out[i << 2]);
    }

    // Scalar tail (n % 4 elements), first few threads of block 0.
    if (blockIdx.x == 0 && tid < ntail) {
        const int v = in_tail[tid];
        out_tail[tid] = ((unsigned)v < NKEYS) ? t[v] : 0.0f;
    }
}

extern "C" void kernel_launch(void* const* d_in, const int* in_sizes, int n_in,
                              void* d_out, int out_size, void* d_ws, size_t ws_size,
                              hipStream_t stream) {
    const int*   x    = (const int*)d_in[0];     // inputs, int32, [8,4096,1024]
    const float* b    = (const float*)d_in[1];   // per-key bias, [64]
    const float* keys = (const float*)d_in[2];   // sorted unique keys, [64]
    float* out = (float*)d_out;

    const int n     = in_sizes[0];
    const int nvec  = n >> 2;       // int4 / float4 groups
    const int ntail = n & 3;

    const int block = 256;
    int grid = (nvec + block - 1) / block;
    if (grid > 8192) grid = 8192;   // grid-stride: ~4 iters/thread at 33.5M elems,
                                    // amortizes table setup + enables 2-deep pipeline
    if (grid < 1) grid = 1;

    sel_xform_kernel<<<grid, block, 0, stream>>>(
        (const int4*)x, b, keys, out,
        nvec, ntail, x + (nvec << 2), out + (nvec << 2));
}

// Round 4
// 229.109 us; speedup vs baseline: 1.0173x; 1.0173x over previous
//
#include <hip/hip_runtime.h>

#define NKEYS 64

typedef float vfloat4 __attribute__((ext_vector_type(4)));

__device__ __forceinline__ float bperm_f(int lane_idx, int src_i) {
    return __int_as_float(__builtin_amdgcn_ds_bpermute(lane_idx << 2, src_i));
}

// out[i] = t[x[i]], t[v] = b[k] iff keys[k] == (float)v, else 0.
// Table lives in registers: lane l of each wave holds t[l], built via a
// 6-step bpermute binary search over the sorted keys. No LDS, no barriers
// -> no s_waitcnt vmcnt(0) drain; bulk input loads stay in flight across
// table construction.
__global__ __launch_bounds__(256) void sel_xform_kernel(
    const int4* __restrict__ in,
    const float* __restrict__ b,
    const float* __restrict__ keys,
    float* __restrict__ out,
    int nvec, int ntail, const int* __restrict__ in_tail, float* __restrict__ out_tail)
{
    const int tid  = threadIdx.x;
    const int lane = tid & 63;

    // Table-source loads FIRST: vmcnt completes in order, so these must be
    // oldest or the table search would wait on the bulk loads below.
    const float kv = keys[lane];   // lane l holds keys[l]
    const float bv = b[lane];      // lane l holds b[l]

    // Bulk input loads: 4 x 16B per thread, all issued before any use.
    const int i0 = blockIdx.x * 1024 + tid;
    const int i1 = i0 + 256, i2 = i0 + 512, i3 = i0 + 768;
    const bool p0 = i0 < nvec, p1 = i1 < nvec, p2 = i2 < nvec, p3 = i3 < nvec;
    int4 v0{}, v1{}, v2{}, v3{};
    if (p0) v0 = in[i0];
    if (p1) v1 = in[i1];
    if (p2) v2 = in[i2];
    if (p3) v3 = in[i3];

    // Per-lane table: lower_bound of (float)lane in keys[0..63].
    const int   kv_i   = __float_as_int(kv);
    const float target = (float)lane;
    int pos = 0;
    #pragma unroll
    for (int s = 32; s >= 1; s >>= 1) {
        const float kc = bperm_f(pos + s - 1, kv_i);   // keys[pos+s-1]
        if (kc < target) pos += s;
    }
    const int posc = (pos > NKEYS - 1) ? (NKEYS - 1) : pos;   // jnp.clip
    const float kmatch = bperm_f(posc, kv_i);
    const float bval   = bperm_f(posc, __float_as_int(bv));
    const int tv_i = (kmatch == target) ? __float_as_int(bval) : 0;  // t[lane]

    // Lookup: t[x] = bpermute(x, t); out-of-range -> 0.
    auto lut = [&](int x) -> float {
        const float r = __int_as_float(__builtin_amdgcn_ds_bpermute(x << 2, tv_i));
        return ((unsigned)x < NKEYS) ? r : 0.0f;
    };

    if (p0) {
        vfloat4 o = { lut(v0.x), lut(v0.y), lut(v0.z), lut(v0.w) };
        *(vfloat4*)(out + ((long)i0 << 2)) = o;
    }
    if (p1) {
        vfloat4 o = { lut(v1.x), lut(v1.y), lut(v1.z), lut(v1.w) };
        *(vfloat4*)(out + ((long)i1 << 2)) = o;
    }
    if (p2) {
        vfloat4 o = { lut(v2.x), lut(v2.y), lut(v2.z), lut(v2.w) };
        *(vfloat4*)(out + ((long)i2 << 2)) = o;
    }
    if (p3) {
        vfloat4 o = { lut(v3.x), lut(v3.y), lut(v3.z), lut(v3.w) };
        *(vfloat4*)(out + ((long)i3 << 2)) = o;
    }

    // Scalar tail (n % 4 elements): uniform scalar search, no cross-lane ops
    // (bpermute under divergent exec reads 0 from inactive source lanes).
    if (blockIdx.x == 0 && tid < ntail) {
        const float xf = (float)in_tail[tid];
        float r = 0.0f;
        for (int k = 0; k < NKEYS; ++k) r = (keys[k] == xf) ? b[k] : r;  // keys unique
        out_tail[tid] = r;
    }
}

extern "C" void kernel_launch(void* const* d_in, const int* in_sizes, int n_in,
                              void* d_out, int out_size, void* d_ws, size_t ws_size,
                              hipStream_t stream) {
    const int*   x    = (const int*)d_in[0];     // inputs, int32, [8,4096,1024]
    const float* b    = (const float*)d_in[1];   // per-key bias, [64]
    const float* keys = (const float*)d_in[2];   // sorted unique keys, [64]
    float* out = (float*)d_out;

    const int n     = in_sizes[0];
    const int nvec  = n >> 2;        // int4 / float4 groups
    const int ntail = n & 3;

    // One batch of 4 int4 per thread -> 1024 int4 per 256-thread block.
    int grid = (nvec + 1023) / 1024;
    if (grid < 1) grid = 1;          // block 0 must exist for the tail

    sel_xform_kernel<<<grid, 256, 0, stream>>>(
        (const int4*)x, b, keys, out,
        nvec, ntail, x + (nvec << 2), out + (nvec << 2));
}